// Round 6
// baseline (1326.829 us; speedup 1.0000x reference)
//
#include <hip/hip_runtime.h>
#include <hip/hip_bf16.h>
#include <math.h>

// ============================================================================
// RAWTextureDetector pipeline, fp32 end-to-end.
//   conv1(4->32)+lrelu -> conv2(32->16)+lrelu -> conv3(16->8)
//   3x multi-scale box-std maps (k=11,25,49, reflect pad) -> fused map
//   exact quantile (radix-histogram select) -> thresholds -> sigmoid mask
// R2: plane_std two-stage full-chip reduction (was 433us @1.3% occupancy).
// R3: hist2/hist3 LDS-merged sub-histograms (was 411us of contended atomics).
// R4: parallel histogram select (was 389us of serial L2-latency bin scans).
// R5: stdmap YB=4 sliding vertical windows + merged 3-scale scan (304->208us).
// R6: conv restructure: 64x16 tile, 4px/thread (acc 64 VGPR not 128),
//     4-channel staging groups (conv2 barriers 64->16), launch_bounds(256,4)
//     for 4 blocks/CU. stdmap: XCD-aware task swizzle (one batch per XCD;
//     FETCH was 131MB for a 64MB input - adjacent blocks were on different
//     XCDs re-fetching the same window rows into private L2s).
// ============================================================================

// ---------------------------------------------------------------------------
// Direct 3x3 conv, zero padding, stride 1. Tile 64x16, 256 threads:
// 16 x-groups of 4 px (tx) x 16 rows (ty). COT output channels per z-group.
// CB=4 input channels staged per barrier pair; LDS row stride 68 floats so
// per-thread reads are aligned float4+float2.
// ---------------------------------------------------------------------------
template<int CIN, int COUT, int COT, bool LRELU>
__global__ __launch_bounds__(256, 4) void conv3x3_k(
    const float* __restrict__ in,   // [nb, CIN, 512, 512]
    const float* __restrict__ wgt,  // [COUT, CIN, 3, 3]
    const float* __restrict__ bias, // [COUT]
    float* __restrict__ out)        // [nb, COUT, 512, 512]
{
    constexpr int TW = 64, TH = 16, CG = COUT / COT, SW = 68, CB = 4;
    constexpr int RPC = (TH + 2) * SW;          // floats per staged channel
    __shared__ float sl[CB * RPC];              // 4 * 18 * 68 * 4B = 19.6 KB

    const int tx  = threadIdx.x & 15;   // x-group (4 px each)
    const int ty  = threadIdx.x >> 4;   // row within tile
    const int x0  = blockIdx.x * TW;
    const int y0  = blockIdx.y * TH;
    const int cog = blockIdx.z % CG;
    const int bb  = blockIdx.z / CG;

    const float* inb = in + (size_t)bb * CIN * 262144;

    float acc[COT][4];
#pragma unroll
    for (int j = 0; j < COT; ++j)
#pragma unroll
        for (int p = 0; p < 4; ++p) acc[j][p] = 0.f;

    for (int cg = 0; cg < CIN / CB; ++cg) {
        __syncthreads();   // protect previous iteration's LDS reads
        const int ci0 = cg * CB;
        for (int idx = threadIdx.x; idx < CB * RPC; idx += 256) {
            int ci  = idx / RPC;
            int rem = idx - ci * RPC;
            int r   = rem / SW;
            int c   = rem - r * SW;
            if (c < TW + 2) {
                int yy = y0 - 1 + r, xx = x0 - 1 + c;
                float v = 0.f;
                if ((unsigned)yy < 512u && (unsigned)xx < 512u)
                    v = inb[(size_t)(ci0 + ci) * 262144 + yy * 512 + xx];
                sl[idx] = v;
            }
        }
        __syncthreads();
#pragma unroll
        for (int ci = 0; ci < CB; ++ci) {
            const float* wci = wgt + ((size_t)(cog * COT) * CIN + ci0 + ci) * 9;
#pragma unroll
            for (int dy = 0; dy < 3; ++dy) {
                const float* rowp = &sl[ci * RPC + (ty + dy) * SW + tx * 4];
                float4 a0 = *(const float4*)rowp;         // cols +0..3
                float2 a1 = *(const float2*)(rowp + 4);   // cols +4..5
                float rr[6] = {a0.x, a0.y, a0.z, a0.w, a1.x, a1.y};
#pragma unroll
                for (int j = 0; j < COT; ++j) {
#pragma unroll
                    for (int dx = 0; dx < 3; ++dx) {
                        float w = wci[(size_t)j * CIN * 9 + dy * 3 + dx];
#pragma unroll
                        for (int p = 0; p < 4; ++p)
                            acc[j][p] = fmaf(rr[p + dx], w, acc[j][p]);
                    }
                }
            }
        }
    }

    const int y = y0 + ty;
#pragma unroll
    for (int j = 0; j < COT; ++j) {
        int co = cog * COT + j;
        float b = bias[co];
        float* op = out + (((size_t)bb * COUT + co) * 512 + y) * 512 + x0 + tx * 4;
        float v[4];
#pragma unroll
        for (int p = 0; p < 4; ++p) {
            float t = acc[j][p] + b;
            if (LRELU) t = t > 0.f ? t : 0.2f * t;
            v[p] = t;
        }
        ((float4*)op)[0] = make_float4(v[0], v[1], v[2], v[3]);
    }
}

// ---------------------------------------------------------------------------
// Multi-scale std map + fusion. Block = (YB output rows, batch), with an
// XCD-aware task swizzle so each XCD owns a contiguous (bb, ytile) span
// (its 49-row x 8-ch working set then stays resident in its private L2).
// ---------------------------------------------------------------------------
__device__ __forceinline__ float2 f2add(float2 a, float2 b) {
    return make_float2(a.x + b.x, a.y + b.y);
}
__device__ __forceinline__ int mir(int v) {
    return v < 0 ? -v : (v > 511 ? 1022 - v : v);
}

#define YB 4

__global__ __launch_bounds__(256) void stdmap_k(
    const float* __restrict__ f,    // [nb, 8, 512, 512]
    const float* __restrict__ fw,   // fusion_w [3]
    const float* __restrict__ fbp,  // fusion_b [1]
    float* __restrict__ fused,      // [8, 512, 512] (global), offset by b0
    int b0)
{
    // XCD swizzle: dispatch round-robins linear block id across 8 XCDs.
    // Give XCD k the contiguous task span [k*total/8, (k+1)*total/8).
    const int total = gridDim.x * gridDim.y;          // 128 * nb
    const int lin   = blockIdx.y * gridDim.x + blockIdx.x;
    const int task  = (lin & 7) * (total >> 3) + (lin >> 3);
    const int bb    = task >> 7;                      // task / 128
    const int y0    = (task & 127) * YB;
    const int t    = threadIdx.x;
    const int lane = t & 63, wid = t >> 6;

    __shared__ float S[3][2][513];   // per-scale prefix arrays (f, f^2)
    __shared__ float wtt[4][6];      // per-wave scan totals, 6 chains

    const int   RAD[3] = {5, 12, 24};
    const float INV[3] = {1.f/121.f, 1.f/625.f, 1.f/2401.f};

    float smacc[3][YB][2];
#pragma unroll
    for (int sc = 0; sc < 3; ++sc)
#pragma unroll
        for (int yy = 0; yy < YB; ++yy)
            { smacc[sc][yy][0] = 0.f; smacc[sc][yy][1] = 0.f; }

    for (int c = 0; c < 8; ++c) {
        const float* base = f + ((size_t)bb * 8 + c) * 512 * 512;

        // ---- initial vertical window sums for y0 (nested rings) ----
        float2 wf[3], wq[3];
        {
            float2 sf[3] = {{0.f,0.f},{0.f,0.f},{0.f,0.f}};
            float2 sq[3] = {{0.f,0.f},{0.f,0.f},{0.f,0.f}};
#pragma unroll
            for (int dy = -24; dy <= 24; ++dy) {
                int row = mir(y0 + dy);
                float2 v  = ((const float2*)(base + (size_t)row * 512))[t];
                float2 vq = make_float2(v.x * v.x, v.y * v.y);
                int ad = dy < 0 ? -dy : dy;
                int ring = ad <= 5 ? 0 : (ad <= 12 ? 1 : 2);
                sf[ring] = f2add(sf[ring], v);
                sq[ring] = f2add(sq[ring], vq);
            }
            wf[0] = sf[0];              wq[0] = sq[0];
            wf[1] = f2add(sf[1], wf[0]); wq[1] = f2add(sq[1], wq[0]);
            wf[2] = f2add(sf[2], wf[1]); wq[2] = f2add(sq[2], wq[1]);
        }

        for (int yy = 0; yy < YB; ++yy) {
            const int y = y0 + yy;
            if (yy > 0) {
                // slide each window: add row mir(y+r), subtract mir(y-1-r)
#pragma unroll
                for (int sc = 0; sc < 3; ++sc) {
                    int ra = mir(y + RAD[sc]);
                    int rs = mir(y - 1 - RAD[sc]);
                    float2 va = ((const float2*)(base + (size_t)ra * 512))[t];
                    float2 vs = ((const float2*)(base + (size_t)rs * 512))[t];
                    wf[sc].x += va.x - vs.x;       wf[sc].y += va.y - vs.y;
                    wq[sc].x += va.x*va.x - vs.x*vs.x;
                    wq[sc].y += va.y*va.y - vs.y*vs.y;
                }
            }

            // ---- merged 3-scale block scan (6 independent chains) ----
            float pf[3], pq[3], incf[3], incq[3];
#pragma unroll
            for (int sc = 0; sc < 3; ++sc) {
                pf[sc] = wf[sc].x + wf[sc].y;
                pq[sc] = wq[sc].x + wq[sc].y;
                incf[sc] = pf[sc]; incq[sc] = pq[sc];
            }
#pragma unroll
            for (int off = 1; off < 64; off <<= 1) {
#pragma unroll
                for (int sc = 0; sc < 3; ++sc) {
                    float uf = __shfl_up(incf[sc], (unsigned)off, 64);
                    float uq = __shfl_up(incq[sc], (unsigned)off, 64);
                    if (lane >= off) { incf[sc] += uf; incq[sc] += uq; }
                }
            }
            if (lane == 63) {
#pragma unroll
                for (int sc = 0; sc < 3; ++sc) {
                    wtt[wid][sc]     = incf[sc];
                    wtt[wid][3 + sc] = incq[sc];
                }
            }
            __syncthreads();
            float wpf[3] = {0.f,0.f,0.f}, wpq[3] = {0.f,0.f,0.f};
#pragma unroll
            for (int w = 0; w < 4; ++w)
                if (w < wid)
#pragma unroll
                    for (int sc = 0; sc < 3; ++sc) {
                        wpf[sc] += wtt[w][sc];
                        wpq[sc] += wtt[w][3 + sc];
                    }
#pragma unroll
            for (int sc = 0; sc < 3; ++sc) {
                float exf = wpf[sc] + incf[sc] - pf[sc];   // exclusive prefix
                float exq = wpq[sc] + incq[sc] - pq[sc];
                S[sc][0][2*t+1] = exf + wf[sc].x;
                S[sc][0][2*t+2] = exf + pf[sc];
                S[sc][1][2*t+1] = exq + wq[sc].x;
                S[sc][1][2*t+2] = exq + pq[sc];
            }
            if (t == 0)
#pragma unroll
                for (int sc = 0; sc < 3; ++sc)
                    { S[sc][0][0] = 0.f; S[sc][1][0] = 0.f; }
            __syncthreads();

            // ---- horizontal window extraction, all 3 scales ----
#pragma unroll
            for (int sc = 0; sc < 3; ++sc) {
                const int r = RAD[sc];
                const float* Sf = S[sc][0];
                const float* Sq = S[sc][1];
#pragma unroll
                for (int slot = 0; slot < 2; ++slot) {
                    int xx = 2*t + slot;
                    int lo = xx - r, hi = xx + r;
                    int loc = lo < 0 ? 0 : lo;
                    int hic = hi > 511 ? 511 : hi;
                    float wfv = Sf[hic + 1] - Sf[loc];
                    float wqv = Sq[hic + 1] - Sq[loc];
                    if (lo < 0)   { wfv += Sf[r - xx + 1] - Sf[1];
                                    wqv += Sq[r - xx + 1] - Sq[1]; }
                    if (hi > 511) { wfv += Sf[511] - Sf[1022 - xx - r];
                                    wqv += Sq[511] - Sq[1022 - xx - r]; }
                    float m   = wfv * INV[sc];
                    float m2  = wqv * INV[sc];
                    float var = m2 - m * m;
                    var = var > 1e-6f ? var : 1e-6f;
                    smacc[sc][yy][slot] += sqrtf(var);
                }
            }
            __syncthreads();   // S/wtt reused next row / next channel
        }
    }

    const float w0 = fw[0], w1 = fw[1], w2 = fw[2], b = fbp[0];
#pragma unroll
    for (int yy = 0; yy < YB; ++yy) {
        float o[2];
#pragma unroll
        for (int slot = 0; slot < 2; ++slot) {
            float m0 = powf(smacc[0][yy][slot] * 0.125f, 0.8f);
            float m1 = powf(smacc[1][yy][slot] * 0.125f, 0.8f);
            float m2 = powf(smacc[2][yy][slot] * 0.125f, 0.8f);
            float fv = w0 * m0 + w1 * m1 + w2 * m2 + b;
            o[slot] = fv > 0.f ? fv : 0.f;
        }
        ((float2*)(fused + ((size_t)(b0 + bb) * 512 + y0 + yy) * 512))[t] =
            make_float2(o[0], o[1]);
    }
}

// ---------------------------------------------------------------------------
// Per-(b,c) plane std of x, ddof=1. Two-stage deterministic reduction.
// ---------------------------------------------------------------------------
__global__ __launch_bounds__(256) void plane_std_part_k(
    const float* __restrict__ x, double* __restrict__ part) // [32][32][2]
{
    const int plane = blockIdx.x >> 5;       // 0..31
    const int blk   = blockIdx.x & 31;       // 0..31
    const float* p = x + (size_t)plane * 262144 + (size_t)blk * 8192;
    double s = 0.0, s2 = 0.0;
    for (int i = threadIdx.x; i < 2048; i += 256) {
        float4 v = ((const float4*)p)[i];
        s  += (double)v.x + (double)v.y + (double)v.z + (double)v.w;
        s2 += (double)v.x * v.x + (double)v.y * v.y
            + (double)v.z * v.z + (double)v.w * v.w;
    }
    __shared__ double ls[256], ls2[256];
    ls[threadIdx.x] = s; ls2[threadIdx.x] = s2;
    __syncthreads();
    for (int off = 128; off > 0; off >>= 1) {
        if (threadIdx.x < off) {
            ls[threadIdx.x]  += ls[threadIdx.x + off];
            ls2[threadIdx.x] += ls2[threadIdx.x + off];
        }
        __syncthreads();
    }
    if (threadIdx.x == 0) {
        part[2 * blockIdx.x]     = ls[0];
        part[2 * blockIdx.x + 1] = ls2[0];
    }
}

__global__ void plane_std_fin_k(const double* __restrict__ part,
                                float* __restrict__ stds)
{
    const int plane = threadIdx.x;
    if (plane >= 32) return;
    double s = 0.0, s2 = 0.0;
    for (int b = 0; b < 32; ++b) {
        s  += part[2 * (plane * 32 + b)];
        s2 += part[2 * (plane * 32 + b) + 1];
    }
    const double N = 262144.0;
    double var = (s2 - s * s / N) / (N - 1.0);
    stds[plane] = (float)sqrt(var > 0.0 ? var : 0.0);
}

// ---------------------------------------------------------------------------
// Exact quantile via 3-level radix histogram (12+12+8 bits) on the uint
// interpretation of the (non-negative) fused values. LDS sub-histograms;
// block-parallel rank select.
// ---------------------------------------------------------------------------
__global__ __launch_bounds__(256) void hist1_k(
    const float* __restrict__ fused, unsigned* __restrict__ h)
{
    __shared__ unsigned lh[4096];
    for (int i = threadIdx.x; i < 4096; i += 256) lh[i] = 0u;
    __syncthreads();
    const int base = blockIdx.x * 2048;
    for (int i = threadIdx.x; i < 2048; i += 256) {
        unsigned bits = __float_as_uint(fused[base + i]);
        atomicAdd(&lh[bits >> 20], 1u);
    }
    __syncthreads();
    for (int i = threadIdx.x; i < 4096; i += 256) {
        unsigned c = lh[i];
        if (c) atomicAdd(&h[i], c);
    }
}

// Parallel rank-select over a 4096-bin histogram. grid = 4 (one block per
// target). level 1: shared h1, rank = quantile targets, pfx = bin<<20.
// level 2: per-target h2 slice, rank = rem[tt], pfx |= bin<<8.
__global__ __launch_bounds__(256) void select_par_k(
    const unsigned* __restrict__ h, unsigned* __restrict__ pfx,
    unsigned* __restrict__ rem, int level)
{
    const int tt = blockIdx.x;
    const int t = threadIdx.x, lane = t & 63, wid = t >> 6;
    const unsigned targets[4] = {524287u, 524288u, 1572863u, 1572864u};
    const unsigned R = (level == 1) ? targets[tt] : rem[tt];
    const unsigned* hb = (level == 1) ? h : h + tt * 4096;

    unsigned loc[16], lsum = 0;
    const uint4* hv = (const uint4*)(hb + t * 16);
#pragma unroll
    for (int i = 0; i < 4; ++i) {
        uint4 v = hv[i];
        loc[4*i]=v.x; loc[4*i+1]=v.y; loc[4*i+2]=v.z; loc[4*i+3]=v.w;
        lsum += v.x + v.y + v.z + v.w;
    }
    // block exclusive scan of per-thread sums
    __shared__ unsigned warr[4];
    __shared__ unsigned rbin, rrem;
    unsigned inc = lsum;
#pragma unroll
    for (int off = 1; off < 64; off <<= 1) {
        unsigned up = __shfl_up(inc, (unsigned)off, 64);
        if (lane >= off) inc += up;
    }
    if (lane == 63) warr[wid] = inc;
    __syncthreads();
    unsigned wpre = 0;
#pragma unroll
    for (int w = 0; w < 4; ++w) if (w < wid) wpre += warr[w];
    unsigned ex = wpre + inc - lsum;
    // exactly one thread's disjoint interval [ex, ex+lsum) contains R
    if (R >= ex && R < ex + lsum) {
        unsigned cum = ex;
#pragma unroll
        for (int i = 0; i < 16; ++i) {
            if (cum + loc[i] > R) { rbin = (unsigned)(t * 16 + i); rrem = R - cum; break; }
            cum += loc[i];
        }
    }
    __syncthreads();
    if (t == 0) {
        if (level == 1) { pfx[tt] = rbin << 20; rem[tt] = rrem; }
        else            { pfx[tt] |= rbin << 8; rem[tt] = rrem; }
    }
}

// grid: 1024 blocks x 2048 elems. LDS [4][4096] = 64 KB sub-histograms.
__global__ __launch_bounds__(256) void hist2_k(
    const float* __restrict__ fused, const unsigned* __restrict__ pfx,
    unsigned* __restrict__ h2)
{
    __shared__ unsigned lh[4 * 4096];
    for (int i = threadIdx.x; i < 4 * 4096; i += 256) lh[i] = 0u;
    unsigned p0 = pfx[0] >> 20, p1 = pfx[1] >> 20,
             p2 = pfx[2] >> 20, p3 = pfx[3] >> 20;
    __syncthreads();
    const int base = blockIdx.x * 2048;
    for (int i = threadIdx.x; i < 2048; i += 256) {
        unsigned bits = __float_as_uint(fused[base + i]);
        unsigned top = bits >> 20;
        unsigned mid = (bits >> 8) & 0xFFFu;
        if (top == p0) atomicAdd(&lh[0 * 4096 + mid], 1u);
        if (top == p1) atomicAdd(&lh[1 * 4096 + mid], 1u);
        if (top == p2) atomicAdd(&lh[2 * 4096 + mid], 1u);
        if (top == p3) atomicAdd(&lh[3 * 4096 + mid], 1u);
    }
    __syncthreads();
    for (int i = threadIdx.x; i < 4 * 4096; i += 256) {
        unsigned c = lh[i];
        if (c) atomicAdd(&h2[i], c);
    }
}

// grid: 1024 blocks x 2048 elems. LDS [4][256] sub-histograms.
__global__ __launch_bounds__(256) void hist3_k(
    const float* __restrict__ fused, const unsigned* __restrict__ pfx,
    unsigned* __restrict__ h3)
{
    __shared__ unsigned lh[4 * 256];
    for (int i = threadIdx.x; i < 4 * 256; i += 256) lh[i] = 0u;
    unsigned p0 = pfx[0] >> 8, p1 = pfx[1] >> 8,
             p2 = pfx[2] >> 8, p3 = pfx[3] >> 8;
    __syncthreads();
    const int base = blockIdx.x * 2048;
    for (int i = threadIdx.x; i < 2048; i += 256) {
        unsigned bits = __float_as_uint(fused[base + i]);
        unsigned top = bits >> 8;
        unsigned low = bits & 0xFFu;
        if (top == p0) atomicAdd(&lh[0 * 256 + low], 1u);
        if (top == p1) atomicAdd(&lh[1 * 256 + low], 1u);
        if (top == p2) atomicAdd(&lh[2 * 256 + low], 1u);
        if (top == p3) atomicAdd(&lh[3 * 256 + low], 1u);
    }
    __syncthreads();
    for (int i = threadIdx.x; i < 4 * 256; i += 256) {
        unsigned c = lh[i];
        if (c) atomicAdd(&h3[i], c);
    }
}

__device__ __forceinline__ float clampf(float v, float lo, float hi) {
    return v < lo ? lo : (v > hi ? hi : v);
}

// Level-3 select (wave-parallel: 4 waves x 64 lanes x 4 bins) + scalar
// threshold math on thread 0.
__global__ __launch_bounds__(256) void finalize_k(
    const unsigned* __restrict__ h3,
    const unsigned* __restrict__ pfx,
    const unsigned* __restrict__ rem,
    const float* __restrict__ stds,
    const float* __restrict__ cw,
    float* __restrict__ lu)
{
    const int tt = threadIdx.x >> 6, lane = threadIdx.x & 63;
    __shared__ float vals[4];

    {
        const unsigned R = rem[tt];
        const unsigned* h = h3 + tt * 256;
        uint4 v = ((const uint4*)h)[lane];
        unsigned loc[4] = {v.x, v.y, v.z, v.w};
        unsigned lsum = v.x + v.y + v.z + v.w;
        unsigned inc = lsum;
#pragma unroll
        for (int off = 1; off < 64; off <<= 1) {
            unsigned up = __shfl_up(inc, (unsigned)off, 64);
            if (lane >= off) inc += up;
        }
        unsigned ex = inc - lsum;
        if (R >= ex && R < ex + lsum) {
            unsigned cum = ex;
#pragma unroll
            for (int i = 0; i < 4; ++i) {
                if (cum + loc[i] > R) {
                    vals[tt] = __uint_as_float(pfx[tt] | (unsigned)(lane * 4 + i));
                    break;
                }
                cum += loc[i];
            }
        }
    }
    __syncthreads();
    if (threadIdx.x != 0) return;

    float q25 = vals[0] + 0.75f * (vals[1] - vals[0]);
    float q75 = vals[2] + 0.25f * (vals[3] - vals[2]);
    float iqr = q75 - q25;
    if (iqr < 1e-5f) iqr = 0.05f;
    float lo0 = q25 - 0.5f * iqr, up0 = q75 + 0.5f * iqr;

    // softmax over channel_weights (4)
    float mx = cw[0];
    for (int c = 1; c < 4; ++c) mx = cw[c] > mx ? cw[c] : mx;
    float e[4], se = 0.f;
    for (int c = 0; c < 4; ++c) { e[c] = expf(cw[c] - mx); se += e[c]; }

    float l[32], u[32], mind = 1e30f;
    for (int p = 0; p < 32; ++p) {
        float sd = stds[p];
        int c = p & 3;
        float gf = clampf(sd * 5.f, 0.5f, 2.f);
        float cf = clampf(sd * (e[c] / se) * 2.f, 0.8f, 1.2f);
        l[p] = lo0 * gf * cf;
        u[p] = up0 * gf * cf;
        float d = fabsf(u[p] - l[p]);
        if (d < mind) mind = d;
    }
    bool deg = mind < 1e-5f;
    for (int p = 0; p < 32; ++p) {
        float L = l[p], U = u[p];
        if (deg) { float m = 0.5f * (L + U); L = m - 0.05f; U = m + 0.05f; }
        lu[p] = L; lu[32 + p] = U;
    }
}

__global__ __launch_bounds__(256) void mask_k(
    const float* __restrict__ fused, const float* __restrict__ lu,
    float* __restrict__ out)
{
    const int b = blockIdx.y;
    const int i = blockIdx.x * 256 + threadIdx.x;
    float fv = fused[(size_t)b * 262144 + i];
    float s = 0.f;
#pragma unroll
    for (int c = 0; c < 4; ++c) {
        float L = lu[b * 4 + c], U = lu[32 + b * 4 + c];
        float d = U - L; d = d > 1e-5f ? d : 1e-5f;
        float n = (fv - L) / d;
        n = n < 0.f ? 0.f : (n > 1.f ? 1.f : n);
        s += 1.f / (1.f + expf(3.f - 6.f * n));
    }
    out[(size_t)b * 262144 + i] = 0.25f * s;
}

// ---------------------------------------------------------------------------
extern "C" void kernel_launch(void* const* d_in, const int* in_sizes, int n_in,
                              void* d_out, int out_size, void* d_ws, size_t ws_size,
                              hipStream_t stream)
{
    const float* x   = (const float*)d_in[0];
    const float* c1w = (const float*)d_in[1];
    const float* c1b = (const float*)d_in[2];
    const float* c2w = (const float*)d_in[3];
    const float* c2b = (const float*)d_in[4];
    const float* c3w = (const float*)d_in[5];
    const float* c3b = (const float*)d_in[6];
    const float* fw  = (const float*)d_in[7];
    const float* fb  = (const float*)d_in[8];
    const float* cwt = (const float*)d_in[9];
    float* out = (float*)d_out;
    char* ws = (char*)d_ws;

    const size_t PLANE = 512 * 512;

    // ws layout: fused | stds | lu | pfx | rem | h1|h2|h3 | partials | chunk
    float* fused = (float*)ws;
    size_t off = 8 * PLANE * sizeof(float);
    float* stds = (float*)(ws + off); off += 32 * 4;
    float* lu   = (float*)(ws + off); off += 64 * 4;
    off = (off + 255) & ~(size_t)255;
    unsigned* pfx = (unsigned*)(ws + off); off += 16;
    unsigned* rem = (unsigned*)(ws + off); off += 16;
    off = (off + 255) & ~(size_t)255;
    unsigned* h1 = (unsigned*)(ws + off); off += 4096 * 4;
    unsigned* h2 = (unsigned*)(ws + off); off += 4 * 4096 * 4;
    unsigned* h3 = (unsigned*)(ws + off); off += 4 * 256 * 4;
    off = (off + 255) & ~(size_t)255;
    double* part = (double*)(ws + off); off += 1024 * 2 * sizeof(double);
    off = (off + 1023) & ~(size_t)1023;

    // chunk buffers: f1(32ch) + f2(16ch) + f(8ch) per batch = 56 planes
    const size_t perb = 56 * PLANE * sizeof(float);
    int nb = 8;
    while (nb > 1 && off + (size_t)nb * perb > ws_size) nb >>= 1;
    float* f1  = (float*)(ws + off);
    float* f2  = f1 + (size_t)nb * 32 * PLANE;
    float* fch = f2 + (size_t)nb * 16 * PLANE;

    hipLaunchKernelGGL(plane_std_part_k, dim3(1024), dim3(256), 0, stream, x, part);
    hipLaunchKernelGGL(plane_std_fin_k,  dim3(1),    dim3(64),  0, stream, part, stds);

    for (int b0 = 0; b0 < 8; b0 += nb) {
        const float* xc = x + (size_t)b0 * 4 * PLANE;
        // conv1: COT=16, CG=2; conv2: COT=16, CG=1; conv3: COT=8, CG=1
        hipLaunchKernelGGL((conv3x3_k<4, 32, 16, true>),  dim3(8, 32, nb * 2),
                           dim3(256), 0, stream, xc, c1w, c1b, f1);
        hipLaunchKernelGGL((conv3x3_k<32, 16, 16, true>), dim3(8, 32, nb),
                           dim3(256), 0, stream, f1, c2w, c2b, f2);
        hipLaunchKernelGGL((conv3x3_k<16, 8, 8, false>),  dim3(8, 32, nb),
                           dim3(256), 0, stream, f2, c3w, c3b, fch);
        hipLaunchKernelGGL(stdmap_k, dim3(512 / YB, nb), dim3(256), 0, stream,
                           fch, fw, fb, fused, b0);
    }

    hipMemsetAsync(h1, 0, (4096 + 4 * 4096 + 4 * 256) * 4, stream);
    hipLaunchKernelGGL(hist1_k,     dim3(1024), dim3(256), 0, stream, fused, h1);
    hipLaunchKernelGGL(select_par_k, dim3(4),   dim3(256), 0, stream, h1, pfx, rem, 1);
    hipLaunchKernelGGL(hist2_k,     dim3(1024), dim3(256), 0, stream, fused, pfx, h2);
    hipLaunchKernelGGL(select_par_k, dim3(4),   dim3(256), 0, stream, h2, pfx, rem, 2);
    hipLaunchKernelGGL(hist3_k,     dim3(1024), dim3(256), 0, stream, fused, pfx, h3);
    hipLaunchKernelGGL(finalize_k,  dim3(1),    dim3(256), 0, stream,
                       h3, pfx, rem, stds, cwt, lu);
    hipLaunchKernelGGL(mask_k, dim3(1024, 8), dim3(256), 0, stream, fused, lu, out);
}

// Round 7
// 1114.494 us; speedup vs baseline: 1.1905x; 1.1905x over previous
//
#include <hip/hip_runtime.h>
#include <hip/hip_bf16.h>
#include <math.h>

// ============================================================================
// RAWTextureDetector pipeline, fp32 end-to-end.
//   fused conv1(4->32)+lrelu & conv2(32->16)+lrelu  ->  conv3(16->8)
//   3x multi-scale box-std maps (k=11,25,49, reflect pad) -> fused map
//   exact quantile (radix-histogram select) -> thresholds -> sigmoid mask
// R2: plane_std two-stage full-chip reduction (was 433us @1.3% occupancy).
// R3: hist2/hist3 LDS-merged sub-histograms (was 411us of contended atomics).
// R4: parallel histogram select (was 389us of serial L2-latency bin scans).
// R5: stdmap YB=4 sliding vertical windows + merged 3-scale scan (304->208us).
// R6 POST-MORTEM: 4px/thread conv regressed conv2 to 266us (FMA density per
//     LDS-read halved); conv2 FETCH=128MB == its whole f1 input (HBM floor
//     167us from materializing f1).
// R7: conv1+conv2 FUSED (f1 lives only in LDS, in 4-channel groups; 256MB of
//     HBM round-trip eliminated); conv3 reverted to the dense R5 structure
//     (8px/thread, 10 LDS floats -> 384 FMA per (ci,dy)).
// ============================================================================

// ---------------------------------------------------------------------------
// Fused conv1+conv2. Block = 64x32 f2-output tile, 256 threads, each owns
// 8 px x 16 f2-channels (acc[16][8]). x halo (68x36, 4ch) staged to LDS once;
// f1 computed group-of-4-channels at a time into LDS (66 used cols x 34 rows,
// zeroed at global OOB so conv2's zero-padding is exact), then consumed.
// LDS: xs 38.3KB + f1s 36.1KB = 76KB -> 2 blocks/CU.
// ---------------------------------------------------------------------------
__global__ __launch_bounds__(256, 2) void conv12_k(
    const float* __restrict__ x,   // [nb, 4, 512, 512]
    const float* __restrict__ w1,  // [32, 4, 3, 3]
    const float* __restrict__ b1,  // [32]
    const float* __restrict__ w2,  // [16, 32, 3, 3]
    const float* __restrict__ b2,  // [16]
    float* __restrict__ f2)        // [nb, 16, 512, 512]
{
    // xs: [4][36][68]  (x at rows y0-2..y0+33, cols x0-2..x0+65, zero-padded)
    // f1s: [4][34][68] (f1 group at rows y0-1..y0+32, cols x0-1..x0+66(pad))
    __shared__ float xs[4 * 36 * 68];    // 9792 floats
    __shared__ float f1s[4 * 34 * 68];   // 9248 floats

    const int t  = threadIdx.x;
    const int tx = t & 7;      // 8 x-groups of 8 px
    const int ty = t >> 3;     // 32 rows
    const int x0 = blockIdx.x * 64;
    const int y0 = blockIdx.y * 32;
    const int bb = blockIdx.z;
    const float* xb = x + (size_t)bb * 4 * 262144;

    // ---- stage x halo (zero-padded) ----
    for (int i = t; i < 9792; i += 256) {
        int ci  = i / 2448;              // 36*68
        int rem = i - ci * 2448;
        int r   = rem / 68;
        int c   = rem - r * 68;
        int Y = y0 - 2 + r, X = x0 - 2 + c;
        float v = 0.f;
        if ((unsigned)Y < 512u && (unsigned)X < 512u)
            v = xb[ci * 262144 + Y * 512 + X];
        xs[i] = v;
    }

    float acc[16][8];
#pragma unroll
    for (int j = 0; j < 16; ++j)
#pragma unroll
        for (int p = 0; p < 8; ++p) acc[j][p] = 0.f;

    for (int g = 0; g < 8; ++g) {
        __syncthreads();   // g=0: xs staged; g>0: prior f1s reads done

        // ---- compute f1 group g (channels g*4 .. g*4+3) into f1s ----
#pragma unroll
        for (int fc = 0; fc < 4; ++fc) {
            const int foc = g * 4 + fc;              // wave-uniform
            float wv[36];
#pragma unroll
            for (int k = 0; k < 36; ++k) wv[k] = w1[foc * 36 + k];
            const float bias = b1[foc];
            // items: 34 rows x 17 quads of 4 px
            for (int it = t; it < 578; it += 256) {
                int r  = it / 17;
                int q  = it - r * 17;
                int c0 = q * 4;
                int Y1 = y0 - 1 + r;
                float v[4] = {bias, bias, bias, bias};
#pragma unroll
                for (int ci = 0; ci < 4; ++ci) {
#pragma unroll
                    for (int ky = 0; ky < 3; ++ky) {
                        const float* xr = &xs[ci * 2448 + (r + ky) * 68 + c0];
                        float4 a  = *(const float4*)xr;
                        float2 bl = *(const float2*)(xr + 4);
                        float rr[6] = {a.x, a.y, a.z, a.w, bl.x, bl.y};
#pragma unroll
                        for (int kx = 0; kx < 3; ++kx) {
                            float w = wv[ci * 9 + ky * 3 + kx];
#pragma unroll
                            for (int p = 0; p < 4; ++p)
                                v[p] = fmaf(rr[p + kx], w, v[p]);
                        }
                    }
                }
                // lrelu + zero at f1-global-OOB (conv2 zero-padding) + pad cols
                float st[4];
                bool rowok = ((unsigned)Y1 < 512u);
#pragma unroll
                for (int p = 0; p < 4; ++p) {
                    int X1 = x0 - 1 + c0 + p;
                    bool ok = rowok && ((unsigned)X1 < 512u) && (c0 + p <= 65);
                    float tv = v[p];
                    tv = tv > 0.f ? tv : 0.2f * tv;
                    st[p] = ok ? tv : 0.f;
                }
                *(float4*)&f1s[fc * 2312 + r * 68 + c0] =
                    make_float4(st[0], st[1], st[2], st[3]);
            }
        }
        __syncthreads();

        // ---- conv2 accumulate from this f1 group ----
#pragma unroll
        for (int fc = 0; fc < 4; ++fc) {
            const int ci = g * 4 + fc;
#pragma unroll
            for (int dy = 0; dy < 3; ++dy) {
                const float* rowp = &f1s[fc * 2312 + (ty + dy) * 68 + tx * 8];
                float4 a0 = *(const float4*)(rowp);
                float4 a1 = *(const float4*)(rowp + 4);
                float2 a2 = *(const float2*)(rowp + 8);
                float rr[10] = {a0.x, a0.y, a0.z, a0.w,
                                a1.x, a1.y, a1.z, a1.w, a2.x, a2.y};
#pragma unroll
                for (int j = 0; j < 16; ++j) {
#pragma unroll
                    for (int dx = 0; dx < 3; ++dx) {
                        float w = w2[(j * 32 + ci) * 9 + dy * 3 + dx];
#pragma unroll
                        for (int p = 0; p < 8; ++p)
                            acc[j][p] = fmaf(rr[p + dx], w, acc[j][p]);
                    }
                }
            }
        }
    }

    // ---- epilogue: bias + lrelu, write f2 ----
    const int y = y0 + ty;
#pragma unroll
    for (int j = 0; j < 16; ++j) {
        float b = b2[j];
        float* op = f2 + (((size_t)bb * 16 + j) * 512 + y) * 512 + x0 + tx * 8;
        float v[8];
#pragma unroll
        for (int p = 0; p < 8; ++p) {
            float tv = acc[j][p] + b;
            v[p] = tv > 0.f ? tv : 0.2f * tv;
        }
        ((float4*)op)[0] = make_float4(v[0], v[1], v[2], v[3]);
        ((float4*)op)[1] = make_float4(v[4], v[5], v[6], v[7]);
    }
}

// ---------------------------------------------------------------------------
// conv3: direct 3x3, zero pad. R5 structure: tile 64x32, 8px/thread, COT=8,
// per-channel LDS staging (dense inner loop: 10 LDS floats -> 192 FMA).
// ---------------------------------------------------------------------------
__global__ __launch_bounds__(256) void conv3_k(
    const float* __restrict__ in,   // [nb, 16, 512, 512]
    const float* __restrict__ wgt,  // [8, 16, 3, 3]
    const float* __restrict__ bias, // [8]
    float* __restrict__ out)        // [nb, 8, 512, 512]
{
    constexpr int TW = 64, TH = 32, SW = TW + 4;
    __shared__ float sl[(TH + 2) * SW];

    const int tx = threadIdx.x & 7;
    const int ty = threadIdx.x >> 3;
    const int x0 = blockIdx.x * TW;
    const int y0 = blockIdx.y * TH;
    const int bb = blockIdx.z;

    const float* inb = in + (size_t)bb * 16 * 262144;

    float acc[8][8];
#pragma unroll
    for (int j = 0; j < 8; ++j)
#pragma unroll
        for (int p = 0; p < 8; ++p) acc[j][p] = 0.f;

    for (int ci = 0; ci < 16; ++ci) {
        __syncthreads();
        const float* ip = inb + (size_t)ci * 262144;
        for (int idx = threadIdx.x; idx < (TH + 2) * (TW + 2); idx += 256) {
            int r  = idx / (TW + 2);
            int cc = idx - r * (TW + 2);
            int yy = y0 - 1 + r, xx = x0 - 1 + cc;
            float v = 0.f;
            if ((unsigned)yy < 512u && (unsigned)xx < 512u) v = ip[yy * 512 + xx];
            sl[r * SW + cc] = v;
        }
        __syncthreads();
        const float* wci = wgt + (size_t)ci * 9;
#pragma unroll
        for (int dy = 0; dy < 3; ++dy) {
            const float* rowp = &sl[(ty + dy) * SW + tx * 8];
            float4 a0 = *(const float4*)(rowp);
            float4 a1 = *(const float4*)(rowp + 4);
            float2 a2 = *(const float2*)(rowp + 8);
            float rr[10] = {a0.x, a0.y, a0.z, a0.w,
                            a1.x, a1.y, a1.z, a1.w, a2.x, a2.y};
#pragma unroll
            for (int j = 0; j < 8; ++j) {
#pragma unroll
                for (int dx = 0; dx < 3; ++dx) {
                    float w = wci[(size_t)j * 16 * 9 + dy * 3 + dx];
#pragma unroll
                    for (int p = 0; p < 8; ++p)
                        acc[j][p] = fmaf(rr[p + dx], w, acc[j][p]);
                }
            }
        }
    }

    const int y = y0 + ty;
#pragma unroll
    for (int j = 0; j < 8; ++j) {
        float b = bias[j];
        float* op = out + (((size_t)bb * 8 + j) * 512 + y) * 512 + x0 + tx * 8;
        float v[8];
#pragma unroll
        for (int p = 0; p < 8; ++p) v[p] = acc[j][p] + b;
        ((float4*)op)[0] = make_float4(v[0], v[1], v[2], v[3]);
        ((float4*)op)[1] = make_float4(v[4], v[5], v[6], v[7]);
    }
}

// ---------------------------------------------------------------------------
// Multi-scale std map + fusion (R5 sliding windows + R6 XCD swizzle).
// ---------------------------------------------------------------------------
__device__ __forceinline__ float2 f2add(float2 a, float2 b) {
    return make_float2(a.x + b.x, a.y + b.y);
}
__device__ __forceinline__ int mir(int v) {
    return v < 0 ? -v : (v > 511 ? 1022 - v : v);
}

#define YB 4

__global__ __launch_bounds__(256) void stdmap_k(
    const float* __restrict__ f,    // [nb, 8, 512, 512]
    const float* __restrict__ fw,   // fusion_w [3]
    const float* __restrict__ fbp,  // fusion_b [1]
    float* __restrict__ fused,      // [8, 512, 512] (global), offset by b0
    int b0)
{
    const int total = gridDim.x * gridDim.y;          // 128 * nb
    const int lin   = blockIdx.y * gridDim.x + blockIdx.x;
    const int task  = (lin & 7) * (total >> 3) + (lin >> 3);
    const int bb    = task >> 7;
    const int y0    = (task & 127) * YB;
    const int t    = threadIdx.x;
    const int lane = t & 63, wid = t >> 6;

    __shared__ float S[3][2][513];
    __shared__ float wtt[4][6];

    const int   RAD[3] = {5, 12, 24};
    const float INV[3] = {1.f/121.f, 1.f/625.f, 1.f/2401.f};

    float smacc[3][YB][2];
#pragma unroll
    for (int sc = 0; sc < 3; ++sc)
#pragma unroll
        for (int yy = 0; yy < YB; ++yy)
            { smacc[sc][yy][0] = 0.f; smacc[sc][yy][1] = 0.f; }

    for (int c = 0; c < 8; ++c) {
        const float* base = f + ((size_t)bb * 8 + c) * 512 * 512;

        float2 wf[3], wq[3];
        {
            float2 sf[3] = {{0.f,0.f},{0.f,0.f},{0.f,0.f}};
            float2 sq[3] = {{0.f,0.f},{0.f,0.f},{0.f,0.f}};
#pragma unroll
            for (int dy = -24; dy <= 24; ++dy) {
                int row = mir(y0 + dy);
                float2 v  = ((const float2*)(base + (size_t)row * 512))[t];
                float2 vq = make_float2(v.x * v.x, v.y * v.y);
                int ad = dy < 0 ? -dy : dy;
                int ring = ad <= 5 ? 0 : (ad <= 12 ? 1 : 2);
                sf[ring] = f2add(sf[ring], v);
                sq[ring] = f2add(sq[ring], vq);
            }
            wf[0] = sf[0];               wq[0] = sq[0];
            wf[1] = f2add(sf[1], wf[0]); wq[1] = f2add(sq[1], wq[0]);
            wf[2] = f2add(sf[2], wf[1]); wq[2] = f2add(sq[2], wq[1]);
        }

        for (int yy = 0; yy < YB; ++yy) {
            const int y = y0 + yy;
            if (yy > 0) {
#pragma unroll
                for (int sc = 0; sc < 3; ++sc) {
                    int ra = mir(y + RAD[sc]);
                    int rs = mir(y - 1 - RAD[sc]);
                    float2 va = ((const float2*)(base + (size_t)ra * 512))[t];
                    float2 vs = ((const float2*)(base + (size_t)rs * 512))[t];
                    wf[sc].x += va.x - vs.x;       wf[sc].y += va.y - vs.y;
                    wq[sc].x += va.x*va.x - vs.x*vs.x;
                    wq[sc].y += va.y*va.y - vs.y*vs.y;
                }
            }

            float pf[3], pq[3], incf[3], incq[3];
#pragma unroll
            for (int sc = 0; sc < 3; ++sc) {
                pf[sc] = wf[sc].x + wf[sc].y;
                pq[sc] = wq[sc].x + wq[sc].y;
                incf[sc] = pf[sc]; incq[sc] = pq[sc];
            }
#pragma unroll
            for (int off = 1; off < 64; off <<= 1) {
#pragma unroll
                for (int sc = 0; sc < 3; ++sc) {
                    float uf = __shfl_up(incf[sc], (unsigned)off, 64);
                    float uq = __shfl_up(incq[sc], (unsigned)off, 64);
                    if (lane >= off) { incf[sc] += uf; incq[sc] += uq; }
                }
            }
            if (lane == 63) {
#pragma unroll
                for (int sc = 0; sc < 3; ++sc) {
                    wtt[wid][sc]     = incf[sc];
                    wtt[wid][3 + sc] = incq[sc];
                }
            }
            __syncthreads();
            float wpf[3] = {0.f,0.f,0.f}, wpq[3] = {0.f,0.f,0.f};
#pragma unroll
            for (int w = 0; w < 4; ++w)
                if (w < wid)
#pragma unroll
                    for (int sc = 0; sc < 3; ++sc) {
                        wpf[sc] += wtt[w][sc];
                        wpq[sc] += wtt[w][3 + sc];
                    }
#pragma unroll
            for (int sc = 0; sc < 3; ++sc) {
                float exf = wpf[sc] + incf[sc] - pf[sc];
                float exq = wpq[sc] + incq[sc] - pq[sc];
                S[sc][0][2*t+1] = exf + wf[sc].x;
                S[sc][0][2*t+2] = exf + pf[sc];
                S[sc][1][2*t+1] = exq + wq[sc].x;
                S[sc][1][2*t+2] = exq + pq[sc];
            }
            if (t == 0)
#pragma unroll
                for (int sc = 0; sc < 3; ++sc)
                    { S[sc][0][0] = 0.f; S[sc][1][0] = 0.f; }
            __syncthreads();

#pragma unroll
            for (int sc = 0; sc < 3; ++sc) {
                const int r = RAD[sc];
                const float* Sf = S[sc][0];
                const float* Sq = S[sc][1];
#pragma unroll
                for (int slot = 0; slot < 2; ++slot) {
                    int xx = 2*t + slot;
                    int lo = xx - r, hi = xx + r;
                    int loc = lo < 0 ? 0 : lo;
                    int hic = hi > 511 ? 511 : hi;
                    float wfv = Sf[hic + 1] - Sf[loc];
                    float wqv = Sq[hic + 1] - Sq[loc];
                    if (lo < 0)   { wfv += Sf[r - xx + 1] - Sf[1];
                                    wqv += Sq[r - xx + 1] - Sq[1]; }
                    if (hi > 511) { wfv += Sf[511] - Sf[1022 - xx - r];
                                    wqv += Sq[511] - Sq[1022 - xx - r]; }
                    float m   = wfv * INV[sc];
                    float m2  = wqv * INV[sc];
                    float var = m2 - m * m;
                    var = var > 1e-6f ? var : 1e-6f;
                    smacc[sc][yy][slot] += sqrtf(var);
                }
            }
            __syncthreads();
        }
    }

    const float w0 = fw[0], w1 = fw[1], w2 = fw[2], b = fbp[0];
#pragma unroll
    for (int yy = 0; yy < YB; ++yy) {
        float o[2];
#pragma unroll
        for (int slot = 0; slot < 2; ++slot) {
            float m0 = powf(smacc[0][yy][slot] * 0.125f, 0.8f);
            float m1 = powf(smacc[1][yy][slot] * 0.125f, 0.8f);
            float m2 = powf(smacc[2][yy][slot] * 0.125f, 0.8f);
            float fv = w0 * m0 + w1 * m1 + w2 * m2 + b;
            o[slot] = fv > 0.f ? fv : 0.f;
        }
        ((float2*)(fused + ((size_t)(b0 + bb) * 512 + y0 + yy) * 512))[t] =
            make_float2(o[0], o[1]);
    }
}

// ---------------------------------------------------------------------------
// Per-(b,c) plane std of x, ddof=1. Two-stage deterministic reduction.
// ---------------------------------------------------------------------------
__global__ __launch_bounds__(256) void plane_std_part_k(
    const float* __restrict__ x, double* __restrict__ part)
{
    const int plane = blockIdx.x >> 5;
    const int blk   = blockIdx.x & 31;
    const float* p = x + (size_t)plane * 262144 + (size_t)blk * 8192;
    double s = 0.0, s2 = 0.0;
    for (int i = threadIdx.x; i < 2048; i += 256) {
        float4 v = ((const float4*)p)[i];
        s  += (double)v.x + (double)v.y + (double)v.z + (double)v.w;
        s2 += (double)v.x * v.x + (double)v.y * v.y
            + (double)v.z * v.z + (double)v.w * v.w;
    }
    __shared__ double ls[256], ls2[256];
    ls[threadIdx.x] = s; ls2[threadIdx.x] = s2;
    __syncthreads();
    for (int off = 128; off > 0; off >>= 1) {
        if (threadIdx.x < off) {
            ls[threadIdx.x]  += ls[threadIdx.x + off];
            ls2[threadIdx.x] += ls2[threadIdx.x + off];
        }
        __syncthreads();
    }
    if (threadIdx.x == 0) {
        part[2 * blockIdx.x]     = ls[0];
        part[2 * blockIdx.x + 1] = ls2[0];
    }
}

__global__ void plane_std_fin_k(const double* __restrict__ part,
                                float* __restrict__ stds)
{
    const int plane = threadIdx.x;
    if (plane >= 32) return;
    double s = 0.0, s2 = 0.0;
    for (int b = 0; b < 32; ++b) {
        s  += part[2 * (plane * 32 + b)];
        s2 += part[2 * (plane * 32 + b) + 1];
    }
    const double N = 262144.0;
    double var = (s2 - s * s / N) / (N - 1.0);
    stds[plane] = (float)sqrt(var > 0.0 ? var : 0.0);
}

// ---------------------------------------------------------------------------
// Exact quantile via 3-level radix histogram (12+12+8 bits).
// ---------------------------------------------------------------------------
__global__ __launch_bounds__(256) void hist1_k(
    const float* __restrict__ fused, unsigned* __restrict__ h)
{
    __shared__ unsigned lh[4096];
    for (int i = threadIdx.x; i < 4096; i += 256) lh[i] = 0u;
    __syncthreads();
    const int base = blockIdx.x * 2048;
    for (int i = threadIdx.x; i < 2048; i += 256) {
        unsigned bits = __float_as_uint(fused[base + i]);
        atomicAdd(&lh[bits >> 20], 1u);
    }
    __syncthreads();
    for (int i = threadIdx.x; i < 4096; i += 256) {
        unsigned c = lh[i];
        if (c) atomicAdd(&h[i], c);
    }
}

__global__ __launch_bounds__(256) void select_par_k(
    const unsigned* __restrict__ h, unsigned* __restrict__ pfx,
    unsigned* __restrict__ rem, int level)
{
    const int tt = blockIdx.x;
    const int t = threadIdx.x, lane = t & 63, wid = t >> 6;
    const unsigned targets[4] = {524287u, 524288u, 1572863u, 1572864u};
    const unsigned R = (level == 1) ? targets[tt] : rem[tt];
    const unsigned* hb = (level == 1) ? h : h + tt * 4096;

    unsigned loc[16], lsum = 0;
    const uint4* hv = (const uint4*)(hb + t * 16);
#pragma unroll
    for (int i = 0; i < 4; ++i) {
        uint4 v = hv[i];
        loc[4*i]=v.x; loc[4*i+1]=v.y; loc[4*i+2]=v.z; loc[4*i+3]=v.w;
        lsum += v.x + v.y + v.z + v.w;
    }
    __shared__ unsigned warr[4];
    __shared__ unsigned rbin, rrem;
    unsigned inc = lsum;
#pragma unroll
    for (int off = 1; off < 64; off <<= 1) {
        unsigned up = __shfl_up(inc, (unsigned)off, 64);
        if (lane >= off) inc += up;
    }
    if (lane == 63) warr[wid] = inc;
    __syncthreads();
    unsigned wpre = 0;
#pragma unroll
    for (int w = 0; w < 4; ++w) if (w < wid) wpre += warr[w];
    unsigned ex = wpre + inc - lsum;
    if (R >= ex && R < ex + lsum) {
        unsigned cum = ex;
#pragma unroll
        for (int i = 0; i < 16; ++i) {
            if (cum + loc[i] > R) { rbin = (unsigned)(t * 16 + i); rrem = R - cum; break; }
            cum += loc[i];
        }
    }
    __syncthreads();
    if (t == 0) {
        if (level == 1) { pfx[tt] = rbin << 20; rem[tt] = rrem; }
        else            { pfx[tt] |= rbin << 8; rem[tt] = rrem; }
    }
}

__global__ __launch_bounds__(256) void hist2_k(
    const float* __restrict__ fused, const unsigned* __restrict__ pfx,
    unsigned* __restrict__ h2)
{
    __shared__ unsigned lh[4 * 4096];
    for (int i = threadIdx.x; i < 4 * 4096; i += 256) lh[i] = 0u;
    unsigned p0 = pfx[0] >> 20, p1 = pfx[1] >> 20,
             p2 = pfx[2] >> 20, p3 = pfx[3] >> 20;
    __syncthreads();
    const int base = blockIdx.x * 2048;
    for (int i = threadIdx.x; i < 2048; i += 256) {
        unsigned bits = __float_as_uint(fused[base + i]);
        unsigned top = bits >> 20;
        unsigned mid = (bits >> 8) & 0xFFFu;
        if (top == p0) atomicAdd(&lh[0 * 4096 + mid], 1u);
        if (top == p1) atomicAdd(&lh[1 * 4096 + mid], 1u);
        if (top == p2) atomicAdd(&lh[2 * 4096 + mid], 1u);
        if (top == p3) atomicAdd(&lh[3 * 4096 + mid], 1u);
    }
    __syncthreads();
    for (int i = threadIdx.x; i < 4 * 4096; i += 256) {
        unsigned c = lh[i];
        if (c) atomicAdd(&h2[i], c);
    }
}

__global__ __launch_bounds__(256) void hist3_k(
    const float* __restrict__ fused, const unsigned* __restrict__ pfx,
    unsigned* __restrict__ h3)
{
    __shared__ unsigned lh[4 * 256];
    for (int i = threadIdx.x; i < 4 * 256; i += 256) lh[i] = 0u;
    unsigned p0 = pfx[0] >> 8, p1 = pfx[1] >> 8,
             p2 = pfx[2] >> 8, p3 = pfx[3] >> 8;
    __syncthreads();
    const int base = blockIdx.x * 2048;
    for (int i = threadIdx.x; i < 2048; i += 256) {
        unsigned bits = __float_as_uint(fused[base + i]);
        unsigned top = bits >> 8;
        unsigned low = bits & 0xFFu;
        if (top == p0) atomicAdd(&lh[0 * 256 + low], 1u);
        if (top == p1) atomicAdd(&lh[1 * 256 + low], 1u);
        if (top == p2) atomicAdd(&lh[2 * 256 + low], 1u);
        if (top == p3) atomicAdd(&lh[3 * 256 + low], 1u);
    }
    __syncthreads();
    for (int i = threadIdx.x; i < 4 * 256; i += 256) {
        unsigned c = lh[i];
        if (c) atomicAdd(&h3[i], c);
    }
}

__device__ __forceinline__ float clampf(float v, float lo, float hi) {
    return v < lo ? lo : (v > hi ? hi : v);
}

__global__ __launch_bounds__(256) void finalize_k(
    const unsigned* __restrict__ h3,
    const unsigned* __restrict__ pfx,
    const unsigned* __restrict__ rem,
    const float* __restrict__ stds,
    const float* __restrict__ cw,
    float* __restrict__ lu)
{
    const int tt = threadIdx.x >> 6, lane = threadIdx.x & 63;
    __shared__ float vals[4];

    {
        const unsigned R = rem[tt];
        const unsigned* h = h3 + tt * 256;
        uint4 v = ((const uint4*)h)[lane];
        unsigned loc[4] = {v.x, v.y, v.z, v.w};
        unsigned lsum = v.x + v.y + v.z + v.w;
        unsigned inc = lsum;
#pragma unroll
        for (int off = 1; off < 64; off <<= 1) {
            unsigned up = __shfl_up(inc, (unsigned)off, 64);
            if (lane >= off) inc += up;
        }
        unsigned ex = inc - lsum;
        if (R >= ex && R < ex + lsum) {
            unsigned cum = ex;
#pragma unroll
            for (int i = 0; i < 4; ++i) {
                if (cum + loc[i] > R) {
                    vals[tt] = __uint_as_float(pfx[tt] | (unsigned)(lane * 4 + i));
                    break;
                }
                cum += loc[i];
            }
        }
    }
    __syncthreads();
    if (threadIdx.x != 0) return;

    float q25 = vals[0] + 0.75f * (vals[1] - vals[0]);
    float q75 = vals[2] + 0.25f * (vals[3] - vals[2]);
    float iqr = q75 - q25;
    if (iqr < 1e-5f) iqr = 0.05f;
    float lo0 = q25 - 0.5f * iqr, up0 = q75 + 0.5f * iqr;

    float mx = cw[0];
    for (int c = 1; c < 4; ++c) mx = cw[c] > mx ? cw[c] : mx;
    float e[4], se = 0.f;
    for (int c = 0; c < 4; ++c) { e[c] = expf(cw[c] - mx); se += e[c]; }

    float l[32], u[32], mind = 1e30f;
    for (int p = 0; p < 32; ++p) {
        float sd = stds[p];
        int c = p & 3;
        float gf = clampf(sd * 5.f, 0.5f, 2.f);
        float cf = clampf(sd * (e[c] / se) * 2.f, 0.8f, 1.2f);
        l[p] = lo0 * gf * cf;
        u[p] = up0 * gf * cf;
        float d = fabsf(u[p] - l[p]);
        if (d < mind) mind = d;
    }
    bool deg = mind < 1e-5f;
    for (int p = 0; p < 32; ++p) {
        float L = l[p], U = u[p];
        if (deg) { float m = 0.5f * (L + U); L = m - 0.05f; U = m + 0.05f; }
        lu[p] = L; lu[32 + p] = U;
    }
}

__global__ __launch_bounds__(256) void mask_k(
    const float* __restrict__ fused, const float* __restrict__ lu,
    float* __restrict__ out)
{
    const int b = blockIdx.y;
    const int i = blockIdx.x * 256 + threadIdx.x;
    float fv = fused[(size_t)b * 262144 + i];
    float s = 0.f;
#pragma unroll
    for (int c = 0; c < 4; ++c) {
        float L = lu[b * 4 + c], U = lu[32 + b * 4 + c];
        float d = U - L; d = d > 1e-5f ? d : 1e-5f;
        float n = (fv - L) / d;
        n = n < 0.f ? 0.f : (n > 1.f ? 1.f : n);
        s += 1.f / (1.f + expf(3.f - 6.f * n));
    }
    out[(size_t)b * 262144 + i] = 0.25f * s;
}

// ---------------------------------------------------------------------------
extern "C" void kernel_launch(void* const* d_in, const int* in_sizes, int n_in,
                              void* d_out, int out_size, void* d_ws, size_t ws_size,
                              hipStream_t stream)
{
    const float* x   = (const float*)d_in[0];
    const float* c1w = (const float*)d_in[1];
    const float* c1b = (const float*)d_in[2];
    const float* c2w = (const float*)d_in[3];
    const float* c2b = (const float*)d_in[4];
    const float* c3w = (const float*)d_in[5];
    const float* c3b = (const float*)d_in[6];
    const float* fw  = (const float*)d_in[7];
    const float* fb  = (const float*)d_in[8];
    const float* cwt = (const float*)d_in[9];
    float* out = (float*)d_out;
    char* ws = (char*)d_ws;

    const size_t PLANE = 512 * 512;

    // ws layout: fused | stds | lu | pfx | rem | h1|h2|h3 | partials | chunk
    float* fused = (float*)ws;
    size_t off = 8 * PLANE * sizeof(float);
    float* stds = (float*)(ws + off); off += 32 * 4;
    float* lu   = (float*)(ws + off); off += 64 * 4;
    off = (off + 255) & ~(size_t)255;
    unsigned* pfx = (unsigned*)(ws + off); off += 16;
    unsigned* rem = (unsigned*)(ws + off); off += 16;
    off = (off + 255) & ~(size_t)255;
    unsigned* h1 = (unsigned*)(ws + off); off += 4096 * 4;
    unsigned* h2 = (unsigned*)(ws + off); off += 4 * 4096 * 4;
    unsigned* h3 = (unsigned*)(ws + off); off += 4 * 256 * 4;
    off = (off + 255) & ~(size_t)255;
    double* part = (double*)(ws + off); off += 1024 * 2 * sizeof(double);
    off = (off + 1023) & ~(size_t)1023;

    // chunk buffers: f2(16ch) + f(8ch) per batch = 24 planes (f1 is LDS-only)
    const size_t perb = 24 * PLANE * sizeof(float);
    int nb = 8;
    while (nb > 1 && off + (size_t)nb * perb > ws_size) nb >>= 1;
    float* f2  = (float*)(ws + off);
    float* fch = f2 + (size_t)nb * 16 * PLANE;

    hipLaunchKernelGGL(plane_std_part_k, dim3(1024), dim3(256), 0, stream, x, part);
    hipLaunchKernelGGL(plane_std_fin_k,  dim3(1),    dim3(64),  0, stream, part, stds);

    for (int b0 = 0; b0 < 8; b0 += nb) {
        const float* xc = x + (size_t)b0 * 4 * PLANE;
        hipLaunchKernelGGL(conv12_k, dim3(8, 16, nb), dim3(256), 0, stream,
                           xc, c1w, c1b, c2w, c2b, f2);
        hipLaunchKernelGGL(conv3_k,  dim3(8, 16, nb), dim3(256), 0, stream,
                           f2, c3w, c3b, fch);
        hipLaunchKernelGGL(stdmap_k, dim3(512 / YB, nb), dim3(256), 0, stream,
                           fch, fw, fb, fused, b0);
    }

    hipMemsetAsync(h1, 0, (4096 + 4 * 4096 + 4 * 256) * 4, stream);
    hipLaunchKernelGGL(hist1_k,     dim3(1024), dim3(256), 0, stream, fused, h1);
    hipLaunchKernelGGL(select_par_k, dim3(4),   dim3(256), 0, stream, h1, pfx, rem, 1);
    hipLaunchKernelGGL(hist2_k,     dim3(1024), dim3(256), 0, stream, fused, pfx, h2);
    hipLaunchKernelGGL(select_par_k, dim3(4),   dim3(256), 0, stream, h2, pfx, rem, 2);
    hipLaunchKernelGGL(hist3_k,     dim3(1024), dim3(256), 0, stream, fused, pfx, h3);
    hipLaunchKernelGGL(finalize_k,  dim3(1),    dim3(256), 0, stream,
                       h3, pfx, rem, stds, cwt, lu);
    hipLaunchKernelGGL(mask_k, dim3(1024, 8), dim3(256), 0, stream, fused, lu, out);
}